// Round 4
// baseline (105.229 us; speedup 1.0000x reference)
//
#include <hip/hip_runtime.h>
#include <math.h>

#define BB 64
#define DD 512
#define HH 8
#define EPS 1e-8f

// Cross-kernel buffers (avoids d_ws size assumptions; legal under graph capture).
__device__ float g_xsorted[BB][DD];
__device__ int   g_perm[BB][DD];

// Raw v_rcp_f32 (~1 ulp). Same instruction+input for m and pass-2 r at the
// argmin -> exact cancellation -> no exp overflow.
__device__ __forceinline__ float fast_rcp(float d) {
    return __builtin_amdgcn_rcpf(d);
}

// ---------------- kernel 1: per-b rank-counting sort (1 barrier) -------------
// rank(i) = #{j : x_j < x_i or (x_j == x_i and j < i)} -> stable permutation.
// Also zeroes `out` (stream-ordered before flattn's atomics) -> no memset.
__global__ __launch_bounds__(DD) void sort_kernel(const float* __restrict__ x,
                                                  float* __restrict__ out)
{
    const int b   = blockIdx.x;
    const int tid = threadIdx.x;
    __shared__ float sv[DD];
    const float xi = x[b * DD + tid];
    sv[tid] = xi;
    out[b * DD + tid] = 0.0f;
    __syncthreads();

    int cnt = 0;
    #pragma unroll 4
    for (int j = 0; j < DD; j += 4) {
        float4 v = *(const float4*)&sv[j];
        cnt += (int)((v.x < xi) | ((v.x == xi) & ((j + 0) < tid)));
        cnt += (int)((v.y < xi) | ((v.y == xi) & ((j + 1) < tid)));
        cnt += (int)((v.z < xi) | ((v.z == xi) & ((j + 2) < tid)));
        cnt += (int)((v.w < xi) | ((v.w == xi) & ((j + 3) < tid)));
    }
    g_xsorted[b][cnt] = xi;
    g_perm[b][cnt]    = tid;
}

// ---------------- kernel 2: attention ---------------------------------------
// Block = 512: (ii, jc) = (tid & 255, tid >> 8). Lane ii handles the i whose
// x-value has sorted rank ic*256+ii -> adjacent lanes have adjacent x_i, so
// per-lane windows are wave-coherent; we take the WAVE-UNION window (shfl
// min/max -> uniform bounds, no divergence, no all-or-nothing gate).
__global__ __launch_bounds__(512, 8) void flattn_kernel(
    const float* __restrict__ x,
    const float* __restrict__ alphas,
    const float* __restrict__ betas,
    float* __restrict__ out)
{
    const int b  = blockIdx.x;
    const int ic = blockIdx.y;
    const int h  = blockIdx.z;

    __shared__ float xs[DD];           // original order (dense path, bitwise r0)
    __shared__ float xss[DD];          // sorted order  (window path)
    __shared__ float mind_sh[2][256];
    __shared__ float ss_sh[256];
    __shared__ float sx_sh[256];

    const int tid  = threadIdx.x;
    const int ii   = tid & 255;
    const int jc   = tid >> 8;         // wave-uniform
    const int rank = ic * 256 + ii;

    const float a0 = alphas[h * 3 + 0];   // block-uniform (h per block)
    const float a1 = alphas[h * 3 + 1];
    const float a2 = alphas[h * 3 + 2];
    const float b0 = betas[h * 3 + 0];
    const float b1 = betas[h * 3 + 1];
    const float b2 = betas[h * 3 + 2];

    xs[tid]  = x[b * DD + tid];
    xss[tid] = g_xsorted[b][tid];
    __syncthreads();

    const float xi = xss[rank];                 // bitwise x[perm[rank]]
    const float c  = b0 - fmaf(a1, xi, b1);     // t_j = a0*x_j + c

    // ---- per-lane conservative window (always CORRECT; flat lanes -> [0,512))
    // Over sorted x, |t| = a0*|x-u| is V-shaped: the true argmin is at rank
    // pos-1 or pos, so mind_hat from the 4 neighbors IS the exact global min.
    int lo = 0, hi = DD;
    float mind_hat = 3.0e38f;
    if (a0 > 1e-6f) {                           // block-uniform branch
        const float ra0 = fast_rcp(a0);
        const float u   = -c * ra0;

        int pos = 0;                            // count of sorted elems < u
        #pragma unroll
        for (int s = 512; s > 0; s >>= 1) {
            int p = pos + s;
            float v = xss[(p <= 512 ? p : 512) - 1];
            pos = (p <= 512 && v < u) ? p : pos;
        }
        #pragma unroll
        for (int q = -2; q <= 1; ++q) {
            int ci = pos + q;
            if (ci >= 0 && ci < DD)
                mind_hat = fminf(mind_hat, fabsf(fmaf(a0, xss[ci], c)));
        }
        const float mhat = fast_rcp(mind_hat + EPS);

        // Keep every j with r_j > m - 30 (dropped mass < 512*e^-30 ~ 5e-11).
        // mhat <= 30 (flat): th -> huge -> window = [0,512) automatically.
        const float th  = fast_rcp(fmaxf(mhat - 30.0f, 1e-30f));
        const float tha = fmaf(th * 1.0001f, ra0, 1e-6f);  // x-space + slack
        const float xlo = u - tha;
        const float xhi = u + tha;

        int l = 0, hc = 0;          // l = count(< xlo), hc = count(<= xhi)
        #pragma unroll
        for (int s = 512; s > 0; s >>= 1) {
            int pl = l + s, ph = hc + s;
            float vl = xss[(pl <= 512 ? pl : 512) - 1];
            float vh = xss[(ph <= 512 ? ph : 512) - 1];
            l  = (pl <= 512 && vl <  xlo) ? pl : l;
            hc = (ph <= 512 && vh <= xhi) ? ph : hc;
        }
        lo = max(l - 2, 0);         // widen: search/rounding insurance
        hi = min(hc + 2, DD);
    }

    // ---- wave-union window: uniform bounds, one bad lane only widens it ----
    int ulo = lo, uhi = hi;
    #pragma unroll
    for (int msk = 1; msk < 64; msk <<= 1) {
        ulo = min(ulo, __shfl_xor(ulo, msk, 64));
        uhi = max(uhi, __shfl_xor(uhi, msk, 64));
    }
    const bool windowed = (uhi - ulo) <= 256;   // wave-uniform by construction

    const float log2e = 1.4426950408889634f;
    const int j0 = jc * 256;

    // ---- pass 1 (dense waves only; windowed waves know the exact min) -----
    if (!windowed) {
        float md = 3.0e38f;
        #pragma unroll 4
        for (int j = j0; j < j0 + 256; j += 4) {
            float4 x4 = *(const float4*)&xs[j];
            md = fminf(md, fabsf(fmaf(a0, x4.x, c)));
            md = fminf(md, fabsf(fmaf(a0, x4.y, c)));
            md = fminf(md, fabsf(fmaf(a0, x4.z, c)));
            md = fminf(md, fabsf(fmaf(a0, x4.w, c)));
        }
        mind_sh[jc][ii] = md;
    }
    __syncthreads();

    float m_;
    if (windowed) {
        m_ = fast_rcp(mind_hat + EPS);          // exact true min (V-shape)
    } else {
        m_ = fast_rcp(fminf(mind_sh[0][ii], mind_sh[1][ii]) + EPS);
    }
    const float negml = -m_ * log2e;

    // ---- pass 2: softmax-weighted sums -------------------------------------
    float ss = 0.0f, sx = 0.0f;
    if (windowed) {
        // float4 over the aligned union, split between jc-halves.
        // Extra terms (within union, outside own window) have r < m_ ->
        // exp underflows toward 0: legitimate tiny terms of the true sum.
        const int base = ulo & ~3;
        const int e4   = min((uhi + 3) & ~3, DD);
        const int nb   = (e4 - base) >> 2;      // # float4 blocks
        const int nbh  = (nb + 1) >> 1;
        const int kb0  = base + ((jc == 0) ? 0 : nbh * 4);
        const int kend = base + ((jc == 0) ? nbh * 4 : nb * 4);
        for (int k = kb0; k < kend; k += 4) {
            float4 x4 = *(const float4*)&xss[k];    // uniform addr: broadcast
            {
                float t = fmaf(a0, x4.x, c);
                float r = fast_rcp(fabsf(t) + EPS);
                float s = __builtin_amdgcn_exp2f(fmaf(r, log2e, negml));
                ss += s; sx = fmaf(s, x4.x, sx);
            }
            {
                float t = fmaf(a0, x4.y, c);
                float r = fast_rcp(fabsf(t) + EPS);
                float s = __builtin_amdgcn_exp2f(fmaf(r, log2e, negml));
                ss += s; sx = fmaf(s, x4.y, sx);
            }
            {
                float t = fmaf(a0, x4.z, c);
                float r = fast_rcp(fabsf(t) + EPS);
                float s = __builtin_amdgcn_exp2f(fmaf(r, log2e, negml));
                ss += s; sx = fmaf(s, x4.z, sx);
            }
            {
                float t = fmaf(a0, x4.w, c);
                float r = fast_rcp(fabsf(t) + EPS);
                float s = __builtin_amdgcn_exp2f(fmaf(r, log2e, negml));
                ss += s; sx = fmaf(s, x4.w, sx);
            }
        }
    } else {
        #pragma unroll 2
        for (int j = j0; j < j0 + 256; j += 4) {
            float4 x4 = *(const float4*)&xs[j];
            {
                float t = fmaf(a0, x4.x, c);
                float r = fast_rcp(fabsf(t) + EPS);
                float s = __builtin_amdgcn_exp2f(fmaf(r, log2e, negml));
                ss += s; sx = fmaf(s, x4.x, sx);
            }
            {
                float t = fmaf(a0, x4.y, c);
                float r = fast_rcp(fabsf(t) + EPS);
                float s = __builtin_amdgcn_exp2f(fmaf(r, log2e, negml));
                ss += s; sx = fmaf(s, x4.y, sx);
            }
            {
                float t = fmaf(a0, x4.z, c);
                float r = fast_rcp(fabsf(t) + EPS);
                float s = __builtin_amdgcn_exp2f(fmaf(r, log2e, negml));
                ss += s; sx = fmaf(s, x4.z, sx);
            }
            {
                float t = fmaf(a0, x4.w, c);
                float r = fast_rcp(fabsf(t) + EPS);
                float s = __builtin_amdgcn_exp2f(fmaf(r, log2e, negml));
                ss += s; sx = fmaf(s, x4.w, sx);
            }
        }
    }

    // ---- merge jc-halves, one atomic per (i, h) ----------------------------
    if (jc == 1) { ss_sh[ii] = ss; sx_sh[ii] = sx; }
    __syncthreads();
    if (jc == 0) {
        ss += ss_sh[ii];
        sx += sx_sh[ii];
        const float scale = 0.04419417382415922f;   // 1/sqrt(512)
        float sv  = fmaf(a2, sx, b2 * ss);
        float att = sv * fast_rcp(ss) * scale;
        if (h == 0) att += xi;
        const int i_orig = g_perm[b][rank];
        atomicAdd(&out[b * DD + i_orig], att);
    }
}

extern "C" void kernel_launch(void* const* d_in, const int* in_sizes, int n_in,
                              void* d_out, int out_size, void* d_ws, size_t ws_size,
                              hipStream_t stream) {
    const float* x      = (const float*)d_in[0];
    const float* alphas = (const float*)d_in[1];
    const float* betas  = (const float*)d_in[2];
    float* out = (float*)d_out;

    sort_kernel<<<dim3(BB), dim3(DD), 0, stream>>>(x, out);

    dim3 grid(BB, 2, HH);
    dim3 block(512);
    flattn_kernel<<<grid, block, 0, stream>>>(x, alphas, betas, out);
}

// Round 5
// 102.197 us; speedup vs baseline: 1.0297x; 1.0297x over previous
//
#include <hip/hip_runtime.h>
#include <math.h>

#define BB 64
#define DD 512
#define HH 8
#define EPS 1e-8f

// Cross-kernel buffers (avoids d_ws size assumptions; legal under graph capture).
__device__ float g_xsorted[BB][DD];
__device__ int   g_perm[BB][DD];

// Raw v_rcp_f32 (~1 ulp). For the windowed/dense paths, same instruction+input
// for m and pass-2 r at the argmin -> exact cancellation -> no exp overflow.
// The flat path needs no cancellation at all (no max subtraction).
__device__ __forceinline__ float fast_rcp(float d) {
    return __builtin_amdgcn_rcpf(d);
}

// ---------------- kernel 1: per-b rank-counting sort (1 barrier) -------------
// rank(i) = #{j : x_j < x_i or (x_j == x_i and j < i)} -> stable permutation.
// Also zeroes `out` (stream-ordered before flattn's atomics) -> no memset.
__global__ __launch_bounds__(DD) void sort_kernel(const float* __restrict__ x,
                                                  float* __restrict__ out)
{
    const int b   = blockIdx.x;
    const int tid = threadIdx.x;
    __shared__ float sv[DD];
    const float xi = x[b * DD + tid];
    sv[tid] = xi;
    out[b * DD + tid] = 0.0f;
    __syncthreads();

    int cnt = 0;
    #pragma unroll 4
    for (int j = 0; j < DD; j += 4) {
        float4 v = *(const float4*)&sv[j];
        cnt += (int)((v.x < xi) | ((v.x == xi) & ((j + 0) < tid)));
        cnt += (int)((v.y < xi) | ((v.y == xi) & ((j + 1) < tid)));
        cnt += (int)((v.z < xi) | ((v.z == xi) & ((j + 2) < tid)));
        cnt += (int)((v.w < xi) | ((v.w == xi) & ((j + 3) < tid)));
    }
    g_xsorted[b][cnt] = xi;
    g_perm[b][cnt]    = tid;
}

// ---------------- kernel 2: attention ---------------------------------------
// Three wave-uniform paths, dispatched on the exact per-lane softmax max
// m-hat (free from sort + binary search; V-shape => argmin in {pos-1,pos}):
//   FLAT    (__all(m<=60), the seed-0 common case per r1's all-fire evidence):
//           no pass 1, no max subtraction (e^m cancels in the ratio),
//           s = exp2(rcp((|t|+EPS)*ln2)): 24 cy/elem vs 30 for r0 (incl p1).
//   WINDOW  (union of per-lane windows <= 256): r4 path, unchanged.
//   DENSE   (fallback): bitwise round-0 two-pass.
__global__ __launch_bounds__(512, 8) void flattn_kernel(
    const float* __restrict__ x,
    const float* __restrict__ alphas,
    const float* __restrict__ betas,
    float* __restrict__ out)
{
    const int b  = blockIdx.x;
    const int ic = blockIdx.y;
    const int h  = blockIdx.z;

    __shared__ float xs[DD];           // original order (flat + dense paths)
    __shared__ float xss[DD];          // sorted order  (prelude + window path)
    __shared__ float mind_sh[2][256];
    __shared__ float ss_sh[256];
    __shared__ float sx_sh[256];

    const int tid  = threadIdx.x;
    const int ii   = tid & 255;
    const int jc   = tid >> 8;         // wave-uniform; waves (w, w+4) pair up
    const int rank = ic * 256 + ii;

    const float a0 = alphas[h * 3 + 0];   // block-uniform (h per block)
    const float a1 = alphas[h * 3 + 1];
    const float a2 = alphas[h * 3 + 2];
    const float b0 = betas[h * 3 + 0];
    const float b1 = betas[h * 3 + 1];
    const float b2 = betas[h * 3 + 2];

    xs[tid]  = x[b * DD + tid];
    xss[tid] = g_xsorted[b][tid];
    __syncthreads();

    const float xi = xss[rank];                 // bitwise x[perm[rank]]
    const float c  = b0 - fmaf(a1, xi, b1);     // t_j = a0*x_j + c

    // ---- prelude: ONE binary search -> exact global min of |t| -------------
    float mind_hat = 3.0e38f;
    float mhat     = 1.0e30f;          // a0 ~ 0 => force DENSE (not flat!)
    float u = 0.0f, ra0 = 0.0f;
    int pos = 0;
    if (a0 > 1e-6f) {                  // block-uniform branch
        ra0 = fast_rcp(a0);
        u   = -c * ra0;
        #pragma unroll
        for (int s = 512; s > 0; s >>= 1) {
            int p = pos + s;
            float v = xss[(p <= 512 ? p : 512) - 1];
            pos = (p <= 512 && v < u) ? p : pos;
        }
        #pragma unroll
        for (int q = -2; q <= 1; ++q) {
            int ci = pos + q;
            if (ci >= 0 && ci < DD)
                mind_hat = fminf(mind_hat, fabsf(fmaf(a0, xss[ci], c)));
        }
        mhat = fast_rcp(mind_hat + EPS);   // EXACT max r (V-shape argmin)
    }

    // Flat gate: m <= 60 => un-subtracted s = exp(r) <= 2^86.6, ss <= 2^96,
    // sx <= 2^98 -- no overflow; e^m cancels exactly in the final ratio.
    const bool flat = __all(mhat <= 60.0f);

    const float log2e = 1.4426950408889634f;
    const int j0 = jc * 256;

    // ---- non-flat: window searches + wave-union ----------------------------
    bool windowed = false;
    int ulo = 0, uhi = DD;
    if (!flat) {
        int lo = 0, hi = DD;
        if (a0 > 1e-6f) {
            // keep every j with r_j > m - 30 (dropped mass < 512*e^-30)
            const float th  = fast_rcp(fmaxf(mhat - 30.0f, 1e-30f));
            const float tha = fmaf(th * 1.0001f, ra0, 1e-6f);
            const float xlo = u - tha;
            const float xhi = u + tha;
            int l = 0, hc = 0;
            #pragma unroll
            for (int s = 512; s > 0; s >>= 1) {
                int pl = l + s, ph = hc + s;
                float vl = xss[(pl <= 512 ? pl : 512) - 1];
                float vh = xss[(ph <= 512 ? ph : 512) - 1];
                l  = (pl <= 512 && vl <  xlo) ? pl : l;
                hc = (ph <= 512 && vh <= xhi) ? ph : hc;
            }
            lo = max(l - 2, 0);
            hi = min(hc + 2, DD);
        }
        ulo = lo; uhi = hi;
        #pragma unroll
        for (int msk = 1; msk < 64; msk <<= 1) {
            ulo = min(ulo, __shfl_xor(ulo, msk, 64));
            uhi = max(uhi, __shfl_xor(uhi, msk, 64));
        }
        windowed = (uhi - ulo) <= 256;     // wave-uniform by construction
    }

    // ---- pass 1 (DENSE waves only) -----------------------------------------
    if (!flat && !windowed) {
        float md = 3.0e38f;
        #pragma unroll 4
        for (int j = j0; j < j0 + 256; j += 4) {
            float4 x4 = *(const float4*)&xs[j];
            md = fminf(md, fabsf(fmaf(a0, x4.x, c)));
            md = fminf(md, fabsf(fmaf(a0, x4.y, c)));
            md = fminf(md, fabsf(fmaf(a0, x4.z, c)));
            md = fminf(md, fabsf(fmaf(a0, x4.w, c)));
        }
        mind_sh[jc][ii] = md;
    }
    __syncthreads();                       // unconditional: all waves

    // ---- pass 2 ------------------------------------------------------------
    float ss = 0.0f, sx = 0.0f;
    if (flat) {
        // No max subtraction: s = exp2(r*log2e), r*log2e = rcp((|t|+EPS)*ln2).
        // (|t|+EPS)*ln2 in ONE fma: |t|*ln2 + EPS*ln2.
        const float LN2    = 0.6931471805599453f;
        const float EPSLN2 = 6.931471805599453e-9f;
        #pragma unroll 2
        for (int j = j0; j < j0 + 256; j += 4) {
            float4 x4 = *(const float4*)&xs[j];
            {
                float t = fmaf(a0, x4.x, c);
                float s = __builtin_amdgcn_exp2f(fast_rcp(fmaf(fabsf(t), LN2, EPSLN2)));
                ss += s; sx = fmaf(s, x4.x, sx);
            }
            {
                float t = fmaf(a0, x4.y, c);
                float s = __builtin_amdgcn_exp2f(fast_rcp(fmaf(fabsf(t), LN2, EPSLN2)));
                ss += s; sx = fmaf(s, x4.y, sx);
            }
            {
                float t = fmaf(a0, x4.z, c);
                float s = __builtin_amdgcn_exp2f(fast_rcp(fmaf(fabsf(t), LN2, EPSLN2)));
                ss += s; sx = fmaf(s, x4.z, sx);
            }
            {
                float t = fmaf(a0, x4.w, c);
                float s = __builtin_amdgcn_exp2f(fast_rcp(fmaf(fabsf(t), LN2, EPSLN2)));
                ss += s; sx = fmaf(s, x4.w, sx);
            }
        }
    } else if (windowed) {
        const float m_    = fast_rcp(mind_hat + EPS);   // exact true min
        const float negml = -m_ * log2e;
        const int base = ulo & ~3;
        const int e4   = min((uhi + 3) & ~3, DD);
        const int nb   = (e4 - base) >> 2;
        const int nbh  = (nb + 1) >> 1;
        const int kb0  = base + ((jc == 0) ? 0 : nbh * 4);
        const int kend = base + ((jc == 0) ? nbh * 4 : nb * 4);
        for (int k = kb0; k < kend; k += 4) {
            float4 x4 = *(const float4*)&xss[k];
            {
                float t = fmaf(a0, x4.x, c);
                float r = fast_rcp(fabsf(t) + EPS);
                float s = __builtin_amdgcn_exp2f(fmaf(r, log2e, negml));
                ss += s; sx = fmaf(s, x4.x, sx);
            }
            {
                float t = fmaf(a0, x4.y, c);
                float r = fast_rcp(fabsf(t) + EPS);
                float s = __builtin_amdgcn_exp2f(fmaf(r, log2e, negml));
                ss += s; sx = fmaf(s, x4.y, sx);
            }
            {
                float t = fmaf(a0, x4.z, c);
                float r = fast_rcp(fabsf(t) + EPS);
                float s = __builtin_amdgcn_exp2f(fmaf(r, log2e, negml));
                ss += s; sx = fmaf(s, x4.z, sx);
            }
            {
                float t = fmaf(a0, x4.w, c);
                float r = fast_rcp(fabsf(t) + EPS);
                float s = __builtin_amdgcn_exp2f(fmaf(r, log2e, negml));
                ss += s; sx = fmaf(s, x4.w, sx);
            }
        }
    } else {
        const float m_    = fast_rcp(fminf(mind_sh[0][ii], mind_sh[1][ii]) + EPS);
        const float negml = -m_ * log2e;
        #pragma unroll 2
        for (int j = j0; j < j0 + 256; j += 4) {
            float4 x4 = *(const float4*)&xs[j];
            {
                float t = fmaf(a0, x4.x, c);
                float r = fast_rcp(fabsf(t) + EPS);
                float s = __builtin_amdgcn_exp2f(fmaf(r, log2e, negml));
                ss += s; sx = fmaf(s, x4.x, sx);
            }
            {
                float t = fmaf(a0, x4.y, c);
                float r = fast_rcp(fabsf(t) + EPS);
                float s = __builtin_amdgcn_exp2f(fmaf(r, log2e, negml));
                ss += s; sx = fmaf(s, x4.y, sx);
            }
            {
                float t = fmaf(a0, x4.z, c);
                float r = fast_rcp(fabsf(t) + EPS);
                float s = __builtin_amdgcn_exp2f(fmaf(r, log2e, negml));
                ss += s; sx = fmaf(s, x4.z, sx);
            }
            {
                float t = fmaf(a0, x4.w, c);
                float r = fast_rcp(fabsf(t) + EPS);
                float s = __builtin_amdgcn_exp2f(fmaf(r, log2e, negml));
                ss += s; sx = fmaf(s, x4.w, sx);
            }
        }
    }

    // ---- merge jc-halves, one atomic per (i, h) ----------------------------
    if (jc == 1) { ss_sh[ii] = ss; sx_sh[ii] = sx; }
    __syncthreads();
    if (jc == 0) {
        ss += ss_sh[ii];
        sx += sx_sh[ii];
        const float scale = 0.04419417382415922f;   // 1/sqrt(512)
        float sv  = fmaf(a2, sx, b2 * ss);
        float att = sv * fast_rcp(ss) * scale;      // e^m (flat) cancels here
        if (h == 0) att += xi;
        const int i_orig = g_perm[b][rank];
        atomicAdd(&out[b * DD + i_orig], att);
    }
}

extern "C" void kernel_launch(void* const* d_in, const int* in_sizes, int n_in,
                              void* d_out, int out_size, void* d_ws, size_t ws_size,
                              hipStream_t stream) {
    const float* x      = (const float*)d_in[0];
    const float* alphas = (const float*)d_in[1];
    const float* betas  = (const float*)d_in[2];
    float* out = (float*)d_out;

    sort_kernel<<<dim3(BB), dim3(DD), 0, stream>>>(x, out);

    dim3 grid(BB, 2, HH);
    dim3 block(512);
    flattn_kernel<<<grid, block, 0, stream>>>(x, alphas, betas, out);
}